// Round 1
// baseline (1014.572 us; speedup 1.0000x reference)
//
#include <hip/hip_runtime.h>
#include <cstdint>
#include <cstddef>

#define NEXP 8

typedef __attribute__((ext_vector_type(8))) short short8;
typedef __attribute__((ext_vector_type(4))) float f32x4;

static __device__ __forceinline__ float bf2f(unsigned short u) {
  union { unsigned int i; float f; } v; v.i = ((unsigned int)u) << 16; return v.f;
}
static __device__ __forceinline__ unsigned short f2bf(float f) {
  union { float f; unsigned int i; } v; v.f = f;
  unsigned int x = v.i;
  return (unsigned short)((x + 0x7fffu + ((x >> 16) & 1u)) >> 16);
}

__device__ __forceinline__ void gload16(const void* g, void* l) {
  __builtin_amdgcn_global_load_lds(
      (const __attribute__((address_space(1))) void*)g,
      (__attribute__((address_space(3))) void*)l, 16, 0, 0);
}

// ---------------------------------------------------------------------------
// Kernel 1: cast concat(z_s,z_e) -> bf16 X, and compute router softmax (fp32)
// grid = B blocks, 256 threads; each block handles one row (1024 elems)
// ---------------------------------------------------------------------------
__global__ __launch_bounds__(256) void cast_router_kernel(
    const float* __restrict__ z_s, const float* __restrict__ z_e,
    const float* __restrict__ rw, const float* __restrict__ rb,
    unsigned short* __restrict__ Xb, float* __restrict__ wts)
{
  const int b = blockIdx.x;
  const int t = threadIdx.x;

  const float* src = (t < 128) ? (z_s + (size_t)b * 512 + t * 4)
                               : (z_e + (size_t)b * 512 + (t - 128) * 4);
  float4 v = *(const float4*)src;

  ushort4 o;
  o.x = f2bf(v.x); o.y = f2bf(v.y); o.z = f2bf(v.z); o.w = f2bf(v.w);
  *(ushort4*)(Xb + (size_t)b * 1024 + t * 4) = o;

  float acc[NEXP];
#pragma unroll
  for (int e = 0; e < NEXP; ++e) acc[e] = 0.f;

  const int k0 = t * 4;
  const float xv[4] = { v.x, v.y, v.z, v.w };
#pragma unroll
  for (int j = 0; j < 4; ++j) {
    const float x = xv[j];
    const float4* rwp = (const float4*)(rw + (size_t)(k0 + j) * NEXP);
    float4 r0 = rwp[0], r1 = rwp[1];
    acc[0] += x * r0.x; acc[1] += x * r0.y; acc[2] += x * r0.z; acc[3] += x * r0.w;
    acc[4] += x * r1.x; acc[5] += x * r1.y; acc[6] += x * r1.z; acc[7] += x * r1.w;
  }

  // wave reduce, then cross-wave via LDS
#pragma unroll
  for (int off = 32; off; off >>= 1) {
#pragma unroll
    for (int e = 0; e < NEXP; ++e) acc[e] += __shfl_xor(acc[e], off);
  }
  __shared__ float red[4][NEXP];
  if ((t & 63) == 0) {
#pragma unroll
    for (int e = 0; e < NEXP; ++e) red[t >> 6][e] = acc[e];
  }
  __syncthreads();
  if (t == 0) {
    float lg[NEXP];
    float mx = -1e30f;
#pragma unroll
    for (int e = 0; e < NEXP; ++e) {
      lg[e] = red[0][e] + red[1][e] + red[2][e] + red[3][e] + rb[e];
      mx = fmaxf(mx, lg[e]);
    }
    float sum = 0.f;
#pragma unroll
    for (int e = 0; e < NEXP; ++e) { lg[e] = expf(lg[e] - mx); sum += lg[e]; }
    const float inv = 1.f / sum;
#pragma unroll
    for (int e = 0; e < NEXP; ++e) wts[(size_t)b * NEXP + e] = lg[e] * inv;
  }
}

// ---------------------------------------------------------------------------
// Kernel 2: transpose+cast weights [E][K=1024][N=1024] fp32 -> [E][N][K] bf16
// grid = (N/32, K/32, E), 256 threads
// ---------------------------------------------------------------------------
__global__ __launch_bounds__(256) void wtrans_kernel(
    const float* __restrict__ w, unsigned short* __restrict__ wt)
{
  __shared__ unsigned short tile[32][33];
  const int e = blockIdx.z;
  const int k0 = blockIdx.y * 32, n0 = blockIdx.x * 32;
  const int tx = threadIdx.x & 31, ty = threadIdx.x >> 5;  // ty 0..7

  const float* wp = w + ((size_t)e << 20) + (size_t)k0 * 1024 + n0;
#pragma unroll
  for (int i = 0; i < 4; ++i) {
    const int kk = ty + i * 8;
    tile[kk][tx] = f2bf(wp[(size_t)kk * 1024 + tx]);
  }
  __syncthreads();
  unsigned short* op = wt + ((size_t)e << 20) + (size_t)n0 * 1024 + k0;
#pragma unroll
  for (int i = 0; i < 4; ++i) {
    const int nn = ty + i * 8;
    op[(size_t)nn * 1024 + tx] = tile[tx][nn];
  }
}

// ---------------------------------------------------------------------------
// Kernel 3: bf16 GEMM, m97 structure. C[m][n] = A[m][:] . Bt[n][:] + bias[n]
// A: [M][1024] bf16 (per-expert stride strideAe), Bt: [E][1024][1024] bf16
// tile 128x128, BK=64, 256 threads = 4 waves (2x2), 4x4 frags of 16x16x32
// grid = (N/128=8, M/128, E)
// ---------------------------------------------------------------------------
template <bool GELU>
__global__ __launch_bounds__(256) void gemm_kernel(
    const unsigned short* __restrict__ A,
    const unsigned short* __restrict__ Bt,
    const float* __restrict__ bias,
    unsigned short* __restrict__ C,
    long long strideAe, long long strideCe)
{
  __shared__ unsigned short As[128 * 64];
  __shared__ unsigned short Bs[128 * 64];

  const int e  = blockIdx.z;
  const int n0 = blockIdx.x * 128;
  const int m0 = blockIdx.y * 128;
  const int t  = threadIdx.x;

  const unsigned short* Ae = A + (size_t)e * strideAe + (size_t)m0 * 1024;
  const unsigned short* Be = Bt + ((size_t)e << 20) + (size_t)n0 * 1024;

  // staging: thread t loads 16B for rows srow+{0,32,64,96}
  const int srow = t >> 3;
  const int scol = (t & 7) * 8;
  const unsigned short* ga = Ae + (size_t)srow * 1024 + scol;
  const unsigned short* gb = Be + (size_t)srow * 1024 + scol;
  unsigned short* la = As + srow * 64 + scol;
  unsigned short* lb = Bs + srow * 64 + scol;

  auto stage = [&](int kt) {
    const unsigned short* ga2 = ga + kt * 64;
    const unsigned short* gb2 = gb + kt * 64;
    gload16(ga2,             la);
    gload16(gb2,             lb);
    gload16(ga2 + 32 * 1024, la + 32 * 64);
    gload16(gb2 + 32 * 1024, lb + 32 * 64);
    gload16(ga2 + 64 * 1024, la + 64 * 64);
    gload16(gb2 + 64 * 1024, lb + 64 * 64);
    gload16(ga2 + 96 * 1024, la + 96 * 64);
    gload16(gb2 + 96 * 1024, lb + 96 * 64);
  };

  const int lane = t & 63;
  const int wid  = t >> 6;
  const int wr   = (wid >> 1) * 64;
  const int wc   = (wid & 1) * 64;
  const int lrow = lane & 15;
  const int lk   = (lane >> 4) * 8;

  f32x4 acc[4][4];
  const f32x4 z4 = { 0.f, 0.f, 0.f, 0.f };
#pragma unroll
  for (int i = 0; i < 4; ++i)
#pragma unroll
    for (int j = 0; j < 4; ++j) acc[i][j] = z4;

  stage(0);
#pragma unroll 1
  for (int kt = 0; kt < 16; ++kt) {
    __syncthreads();  // staged tile visible (compiler drains vmcnt before barrier)
#pragma unroll
    for (int ks = 0; ks < 2; ++ks) {
      short8 af[4], bfr[4];
#pragma unroll
      for (int i = 0; i < 4; ++i)
        af[i] = *(const short8*)&As[(wr + i * 16 + lrow) * 64 + ks * 32 + lk];
#pragma unroll
      for (int j = 0; j < 4; ++j)
        bfr[j] = *(const short8*)&Bs[(wc + j * 16 + lrow) * 64 + ks * 32 + lk];
#pragma unroll
      for (int i = 0; i < 4; ++i)
#pragma unroll
        for (int j = 0; j < 4; ++j)
          acc[i][j] = __builtin_amdgcn_mfma_f32_16x16x32_bf16(af[i], bfr[j], acc[i][j], 0, 0, 0);
    }
    __syncthreads();  // all waves done reading LDS
    if (kt < 15) stage(kt + 1);
  }

  // epilogue: C/D layout col = lane&15, row = (lane>>4)*4 + reg
  const float* be2 = bias + (size_t)e * 1024 + n0;
  unsigned short* Ce = C + (size_t)e * strideCe + (size_t)m0 * 1024 + n0;
  const int crow = (lane >> 4) * 4;
  const int ccol = lane & 15;
#pragma unroll
  for (int i = 0; i < 4; ++i) {
#pragma unroll
    for (int j = 0; j < 4; ++j) {
      const int col = wc + j * 16 + ccol;
      const float bv = be2[col];
#pragma unroll
      for (int r = 0; r < 4; ++r) {
        const int row = wr + i * 16 + crow + r;
        float v = acc[i][j][r] + bv;
        if (GELU) v = 0.5f * v * (1.0f + erff(v * 0.70710678118654752f));
        Ce[(size_t)row * 1024 + col] = f2bf(v);
      }
    }
  }
}

// ---------------------------------------------------------------------------
// Kernel 4: per-expert LayerNorm + softmax-weighted sum over experts
// grid = Bc blocks, 512 threads = 8 waves (one per expert)
// ---------------------------------------------------------------------------
__global__ __launch_bounds__(512) void finalize_kernel(
    const unsigned short* __restrict__ y,   // [E][Bc][1024] bf16
    const float* __restrict__ wts,          // [B][8] fp32 (global index)
    const float* __restrict__ gamma,
    const float* __restrict__ beta,
    float* __restrict__ zout,               // [B][1024] fp32
    int Bc, int bbase)
{
  __shared__ float zacc[NEXP][1024];
  const int brow = blockIdx.x;
  const int t = threadIdx.x;
  const int e = t >> 6;
  const int lane = t & 63;

  const unsigned short* yp = y + ((size_t)e * Bc + brow) * 1024;
  short8 v0 = *(const short8*)(yp + lane * 8);
  short8 v1 = *(const short8*)(yp + 512 + lane * 8);

  float f0[8], f1[8];
  float s = 0.f, sq = 0.f;
#pragma unroll
  for (int j = 0; j < 8; ++j) {
    f0[j] = bf2f((unsigned short)v0[j]);
    f1[j] = bf2f((unsigned short)v1[j]);
    s += f0[j] + f1[j];
    sq += f0[j] * f0[j] + f1[j] * f1[j];
  }
#pragma unroll
  for (int off = 32; off; off >>= 1) {
    s  += __shfl_xor(s, off);
    sq += __shfl_xor(sq, off);
  }
  const float mu  = s * (1.f / 1024.f);
  const float var = sq * (1.f / 1024.f) - mu * mu;
  const float rs  = rsqrtf(var + 1e-5f);
  const float w   = wts[(size_t)(bbase + brow) * NEXP + e];

  const int c0 = lane * 8;
#pragma unroll
  for (int j = 0; j < 8; ++j) {
    const int ca = c0 + j, cb = 512 + c0 + j;
    zacc[e][ca] = w * ((f0[j] - mu) * rs * gamma[e * 1024 + ca] + beta[e * 1024 + ca]);
    zacc[e][cb] = w * ((f1[j] - mu) * rs * gamma[e * 1024 + cb] + beta[e * 1024 + cb]);
  }
  __syncthreads();
  float r0 = 0.f, r1 = 0.f;
#pragma unroll
  for (int ee = 0; ee < NEXP; ++ee) { r0 += zacc[ee][t]; r1 += zacc[ee][t + 512]; }
  float* zp = zout + (size_t)(bbase + brow) * 1024;
  zp[t] = r0;
  zp[t + 512] = r1;
}

// ---------------------------------------------------------------------------
extern "C" void kernel_launch(void* const* d_in, const int* in_sizes, int n_in,
                              void* d_out, int out_size, void* d_ws, size_t ws_size,
                              hipStream_t stream)
{
  const float* z_s      = (const float*)d_in[0];
  const float* z_e      = (const float*)d_in[1];
  const float* router_w = (const float*)d_in[2];
  const float* router_b = (const float*)d_in[3];
  const float* w1       = (const float*)d_in[4];
  const float* b1       = (const float*)d_in[5];
  const float* w2       = (const float*)d_in[6];
  const float* b2       = (const float*)d_in[7];
  const float* gamma    = (const float*)d_in[8];
  const float* beta     = (const float*)d_in[9];
  float* zout = (float*)d_out;

  const int B = 16384;

  // workspace layout
  char* ws = (char*)d_ws;
  unsigned short* Xb  = (unsigned short*)ws;                      // 33,554,432 B
  unsigned short* W1t = (unsigned short*)(ws + 33554432);         // 16,777,216 B
  unsigned short* W2t = W1t + ((size_t)8 << 20);                  // 16,777,216 B
  float* wts = (float*)(ws + 33554432 + 2 * 16777216);            //    524,288 B
  const size_t persist = 33554432 + 2 * 16777216 + 524288;        // 67,633,152 B
  char* dyn = ws + persist;
  const size_t rem = (ws_size > persist) ? (ws_size - persist) : 0;

  int nch = 1;
  while ((size_t)(B / nch) * 32768ull > rem && nch < 128) nch <<= 1;
  const int Bc = B / nch;

  unsigned short* hbuf = (unsigned short*)dyn;                    // Bc*8*1024 bf16
  unsigned short* ybuf = hbuf + (size_t)Bc * 8 * 1024;            // Bc*8*1024 bf16

  cast_router_kernel<<<B, 256, 0, stream>>>(z_s, z_e, router_w, router_b, Xb, wts);
  wtrans_kernel<<<dim3(32, 32, 8), 256, 0, stream>>>(w1, W1t);
  wtrans_kernel<<<dim3(32, 32, 8), 256, 0, stream>>>(w2, W2t);

  for (int c = 0; c < nch; ++c) {
    const int bbase = c * Bc;
    gemm_kernel<true><<<dim3(8, Bc / 128, 8), 256, 0, stream>>>(
        Xb + (size_t)bbase * 1024, W1t, b1, hbuf, 0ll, (long long)Bc * 1024);
    gemm_kernel<false><<<dim3(8, Bc / 128, 8), 256, 0, stream>>>(
        hbuf, W2t, b2, ybuf, (long long)Bc * 1024, (long long)Bc * 1024);
    finalize_kernel<<<Bc, 512, 0, stream>>>(ybuf, wts, gamma, beta, zout, Bc, bbase);
  }
}

// Round 2
// 840.393 us; speedup vs baseline: 1.2073x; 1.2073x over previous
//
#include <hip/hip_runtime.h>
#include <cstdint>
#include <cstddef>

#define NEXP 8

typedef __attribute__((ext_vector_type(8))) short short8;
typedef __attribute__((ext_vector_type(4))) float f32x4;

static __device__ __forceinline__ float bf2f(unsigned short u) {
  union { unsigned int i; float f; } v; v.i = ((unsigned int)u) << 16; return v.f;
}
static __device__ __forceinline__ unsigned short f2bf(float f) {
  union { float f; unsigned int i; } v; v.f = f;
  unsigned int x = v.i;
  return (unsigned short)((x + 0x7fffu + ((x >> 16) & 1u)) >> 16);
}

__device__ __forceinline__ void gload16(const void* g, void* l) {
  __builtin_amdgcn_global_load_lds(
      (const __attribute__((address_space(1))) void*)g,
      (__attribute__((address_space(3))) void*)l, 16, 0, 0);
}

#define BAR() __builtin_amdgcn_s_barrier()
#define WAIT_LGKM0() asm volatile("s_waitcnt lgkmcnt(0)" ::: "memory")

// ---------------------------------------------------------------------------
// Kernel 1: cast concat(z_s,z_e) -> bf16 X, and compute router softmax (fp32)
// ---------------------------------------------------------------------------
__global__ __launch_bounds__(256) void cast_router_kernel(
    const float* __restrict__ z_s, const float* __restrict__ z_e,
    const float* __restrict__ rw, const float* __restrict__ rb,
    unsigned short* __restrict__ Xb, float* __restrict__ wts)
{
  const int b = blockIdx.x;
  const int t = threadIdx.x;

  const float* src = (t < 128) ? (z_s + (size_t)b * 512 + t * 4)
                               : (z_e + (size_t)b * 512 + (t - 128) * 4);
  float4 v = *(const float4*)src;

  ushort4 o;
  o.x = f2bf(v.x); o.y = f2bf(v.y); o.z = f2bf(v.z); o.w = f2bf(v.w);
  *(ushort4*)(Xb + (size_t)b * 1024 + t * 4) = o;

  float acc[NEXP];
#pragma unroll
  for (int e = 0; e < NEXP; ++e) acc[e] = 0.f;

  const int k0 = t * 4;
  const float xv[4] = { v.x, v.y, v.z, v.w };
#pragma unroll
  for (int j = 0; j < 4; ++j) {
    const float x = xv[j];
    const float4* rwp = (const float4*)(rw + (size_t)(k0 + j) * NEXP);
    float4 r0 = rwp[0], r1 = rwp[1];
    acc[0] += x * r0.x; acc[1] += x * r0.y; acc[2] += x * r0.z; acc[3] += x * r0.w;
    acc[4] += x * r1.x; acc[5] += x * r1.y; acc[6] += x * r1.z; acc[7] += x * r1.w;
  }

#pragma unroll
  for (int off = 32; off; off >>= 1) {
#pragma unroll
    for (int e = 0; e < NEXP; ++e) acc[e] += __shfl_xor(acc[e], off);
  }
  __shared__ float red[4][NEXP];
  if ((t & 63) == 0) {
#pragma unroll
    for (int e = 0; e < NEXP; ++e) red[t >> 6][e] = acc[e];
  }
  __syncthreads();
  if (t == 0) {
    float lg[NEXP];
    float mx = -1e30f;
#pragma unroll
    for (int e = 0; e < NEXP; ++e) {
      lg[e] = red[0][e] + red[1][e] + red[2][e] + red[3][e] + rb[e];
      mx = fmaxf(mx, lg[e]);
    }
    float sum = 0.f;
#pragma unroll
    for (int e = 0; e < NEXP; ++e) { lg[e] = expf(lg[e] - mx); sum += lg[e]; }
    const float inv = 1.f / sum;
#pragma unroll
    for (int e = 0; e < NEXP; ++e) wts[(size_t)b * NEXP + e] = lg[e] * inv;
  }
}

// ---------------------------------------------------------------------------
// Kernel 2: transpose+cast weights [E][K=1024][N=1024] fp32 -> [E][N][K] bf16
// ---------------------------------------------------------------------------
__global__ __launch_bounds__(256) void wtrans_kernel(
    const float* __restrict__ w, unsigned short* __restrict__ wt)
{
  __shared__ unsigned short tile[32][33];
  const int e = blockIdx.z;
  const int k0 = blockIdx.y * 32, n0 = blockIdx.x * 32;
  const int tx = threadIdx.x & 31, ty = threadIdx.x >> 5;

  const float* wp = w + ((size_t)e << 20) + (size_t)k0 * 1024 + n0;
#pragma unroll
  for (int i = 0; i < 4; ++i) {
    const int kk = ty + i * 8;
    tile[kk][tx] = f2bf(wp[(size_t)kk * 1024 + tx]);
  }
  __syncthreads();
  unsigned short* op = wt + ((size_t)e << 20) + (size_t)n0 * 1024 + k0;
#pragma unroll
  for (int i = 0; i < 4; ++i) {
    const int nn = ty + i * 8;
    op[(size_t)nn * 1024 + tx] = tile[tx][nn];
  }
}

// ---------------------------------------------------------------------------
// Kernel 3: 256x256 8-phase bf16 GEMM (T1+T2+T3+T4+T5), K=1024 fixed.
// C[m][n] = A[m][:] . Bt[n][:] + bias[n]  (optional exact GELU)
// A: [M][1024] bf16 (per-expert stride strideAe), Bt: [E][1024][1024] bf16
// 512 threads = 8 waves (2M x 4N); per-wave 128x64 out; BK=64, NT=16, NI=8.
// LDS 128KB: buf d in ushorts: A at d*32768 + h*8192, B at 16384 + d*32768 + h*8192.
// XOR swizzle: 16B slot s at row r holds source slot s ^ (r&7)  (linear
// global_load_lds dest + pre-swizzled global source; swizzled ds_read).
// grid: 1D nwg = mtiles*4*8 (XCD-bijective swizzle, nwg%8==0).
// ---------------------------------------------------------------------------
template <bool GELU>
__global__ __launch_bounds__(512, 2) void gemm8_kernel(
    const unsigned short* __restrict__ A,
    const unsigned short* __restrict__ Bt,
    const float* __restrict__ bias,
    unsigned short* __restrict__ C,
    long long strideAe, long long strideCe, int mtiles)
{
  __shared__ unsigned short lds[65536];  // 128 KB

  const int nwg = gridDim.x;
  const int cpx = nwg >> 3;
  const int bid = blockIdx.x;
  const int swz = (bid & 7) * cpx + (bid >> 3);
  const int e   = swz / (mtiles << 2);
  const int rem = swz - e * (mtiles << 2);
  const int m0  = (rem >> 2) << 8;
  const int n0  = (rem & 3) << 8;

  const int t   = threadIdx.x;
  const int l   = t & 63;
  const int wid = t >> 6;
  const int wm  = wid >> 2;   // 0..1
  const int wn  = wid & 3;    // 0..3

  const unsigned short* Ae = A + (size_t)e * strideAe + (size_t)m0 * 1024;
  const unsigned short* Be = Bt + ((size_t)e << 20) + (size_t)n0 * 1024;

  // staging: thread t covers dest idx {t, t+512} of a 128x64 half-region.
  // dest linear byte = idx*16 -> row = idx>>3, slot = idx&7; source slot = slot ^ (row&7)
  const int sr = t >> 3;                          // row (j=0); j=1 adds 64
  const int ss = ((t & 7) ^ ((t >> 3) & 7)) * 8;  // swizzled source col (ushorts)

  auto stageA = [&](int d, int h, int T) {
    const unsigned short* g = Ae + (size_t)(h * 128 + sr) * 1024 + T * 64 + ss;
    unsigned short* lp = lds + d * 32768 + h * 8192 + t * 8;
    gload16(g, lp);
    gload16(g + 65536, lp + 4096);
  };
  auto stageB = [&](int d, int h, int T) {
    const unsigned short* g = Be + (size_t)(h * 128 + sr) * 1024 + T * 64 + ss;
    unsigned short* lp = lds + 16384 + d * 32768 + h * 8192 + t * 8;
    gload16(g, lp);
    gload16(g + 65536, lp + 4096);
  };

  // ds-read: lane l wants row-in-region rr (rr&7 == l&7) at slot ks*4 + (l>>4);
  // swizzled slot = (ks*4 + (l>>4)) ^ (l&7)
  const int kq  = (l >> 4) ^ (l & 3);
  const int b2p = (l >> 2) & 1;
  const int sl0 = ((b2p << 2) | kq) * 8;
  const int sl1 = (((b2p ^ 1) << 2) | kq) * 8;
  const int aR = wm * 8192 + (l & 15) * 64;                    // + d*32768 + mi*1024
  const int bR = 16384 + (wn >> 1) * 8192 + (wn & 1) * 4096 + (l & 15) * 64;

  short8 a[4][2], b0[2][2], b1[2][2];
  f32x4 acc[8][4];
#pragma unroll
  for (int i = 0; i < 8; ++i)
#pragma unroll
    for (int j = 0; j < 4; ++j) acc[i][j] = (f32x4){0.f, 0.f, 0.f, 0.f};

  auto ldA = [&](int d, int q) {
#pragma unroll
    for (int m = 0; m < 4; ++m) {
      const unsigned short* p = lds + d * 32768 + aR + (q * 4 + m) * 1024;
      a[m][0] = *(const short8*)(p + sl0);
      a[m][1] = *(const short8*)(p + sl1);
    }
  };
  auto ldB = [&](int d, int q, short8 (&br)[2][2]) {
#pragma unroll
    for (int n = 0; n < 2; ++n) {
      const unsigned short* p = lds + d * 32768 + bR + (q * 2 + n) * 1024;
      br[n][0] = *(const short8*)(p + sl0);
      br[n][1] = *(const short8*)(p + sl1);
    }
  };
  auto mmac = [&](int aq, int bq, short8 (&br)[2][2]) {
    __builtin_amdgcn_s_setprio(1);
#pragma unroll
    for (int ks = 0; ks < 2; ++ks)
#pragma unroll
      for (int m = 0; m < 4; ++m)
#pragma unroll
        for (int n = 0; n < 2; ++n)
          acc[aq * 4 + m][bq * 2 + n] = __builtin_amdgcn_mfma_f32_16x16x32_bf16(
              a[m][ks], br[n][ks], acc[aq * 4 + m][bq * 2 + n], 0, 0, 0);
    __builtin_amdgcn_s_setprio(0);
  };

  // prologue: T0 all 4 halves; T1 {B-h0, B-h1, A-h0} (A-h1 staged at P1)
  stageA(0, 0, 0); stageA(0, 1, 0); stageB(0, 0, 0); stageB(0, 1, 0);
  stageB(1, 0, 1); stageB(1, 1, 1); stageA(1, 0, 1);
  asm volatile("s_waitcnt vmcnt(6)" ::: "memory");
  BAR();

#pragma unroll 1
  for (int i = 0; i < 8; ++i) {
    const bool nl = (i < 7);
    const int T1 = 2 * i + 1, T2 = 2 * i + 2, T3 = 2 * i + 3;
    // P1: read buf0 A-quad0 + B-quad0; stage buf1.A-h1 <- T1
    ldA(0, 0); ldB(0, 0, b0); stageA(1, 1, T1);
    BAR(); WAIT_LGKM0();
    mmac(0, 0, b0);
    BAR();
    // P2: read buf0 B-quad1
    ldB(0, 1, b1);
    BAR(); WAIT_LGKM0();
    mmac(0, 1, b1);
    BAR();
    // P3: read buf0 A-quad1; stage buf0.B-h0 <- T2 (B regions free after P2)
    ldA(0, 1);
    if (nl) stageB(0, 0, T2);
    BAR(); WAIT_LGKM0();
    mmac(1, 1, b1);
    BAR();
    // P4: stage buf0.B-h1 + buf0.A-h0 <- T2 (A regions free after P3); vmcnt
    if (nl) { stageB(0, 1, T2); stageA(0, 0, T2); }
    BAR();
    mmac(1, 0, b0);
    if (nl) asm volatile("s_waitcnt vmcnt(6)" ::: "memory");
    else    asm volatile("s_waitcnt vmcnt(0)" ::: "memory");
    BAR();
    // P5: read buf1 A-quad0 + B-quad0; stage buf0.A-h1 <- T2
    ldA(1, 0); ldB(1, 0, b0);
    if (nl) stageA(0, 1, T2);
    BAR(); WAIT_LGKM0();
    mmac(0, 0, b0);
    BAR();
    // P6: read buf1 B-quad1
    ldB(1, 1, b1);
    BAR(); WAIT_LGKM0();
    mmac(0, 1, b1);
    BAR();
    // P7: read buf1 A-quad1; stage buf1.B-h0 <- T3
    ldA(1, 1);
    if (nl) stageB(1, 0, T3);
    BAR(); WAIT_LGKM0();
    mmac(1, 1, b1);
    BAR();
    // P8: stage buf1.B-h1 + buf1.A-h0 <- T3; vmcnt
    if (nl) { stageB(1, 1, T3); stageA(1, 0, T3); }
    BAR();
    mmac(1, 0, b0);
    if (nl) asm volatile("s_waitcnt vmcnt(6)" ::: "memory");
    BAR();
  }

  // epilogue: C/D layout col = lane&15, row = (lane>>4)*4 + reg
  const float* bp = bias + (size_t)e * 1024 + n0 + wn * 64;
  unsigned short* Ce = C + (size_t)e * strideCe + (size_t)(m0 + wm * 128) * 1024 + n0 + wn * 64;
  const int cr = (l >> 4) * 4, cc = l & 15;
#pragma unroll
  for (int mi = 0; mi < 8; ++mi) {
#pragma unroll
    for (int ni = 0; ni < 4; ++ni) {
      const int col = ni * 16 + cc;
      const float bv = bp[col];
#pragma unroll
      for (int r = 0; r < 4; ++r) {
        float v = acc[mi][ni][r] + bv;
        if (GELU) v = 0.5f * v * (1.0f + erff(v * 0.70710678118654752f));
        Ce[(size_t)(mi * 16 + cr + r) * 1024 + col] = f2bf(v);
      }
    }
  }
}

// ---------------------------------------------------------------------------
// Kernel 4: per-expert LayerNorm + softmax-weighted sum over experts
// ---------------------------------------------------------------------------
__global__ __launch_bounds__(512) void finalize_kernel(
    const unsigned short* __restrict__ y,   // [E][Bc][1024] bf16
    const float* __restrict__ wts,
    const float* __restrict__ gamma,
    const float* __restrict__ beta,
    float* __restrict__ zout,
    int Bc, int bbase)
{
  __shared__ float zacc[NEXP][1024];
  const int brow = blockIdx.x;
  const int t = threadIdx.x;
  const int e = t >> 6;
  const int lane = t & 63;

  const unsigned short* yp = y + ((size_t)e * Bc + brow) * 1024;
  short8 v0 = *(const short8*)(yp + lane * 8);
  short8 v1 = *(const short8*)(yp + 512 + lane * 8);

  float f0[8], f1[8];
  float s = 0.f, sq = 0.f;
#pragma unroll
  for (int j = 0; j < 8; ++j) {
    f0[j] = bf2f((unsigned short)v0[j]);
    f1[j] = bf2f((unsigned short)v1[j]);
    s += f0[j] + f1[j];
    sq += f0[j] * f0[j] + f1[j] * f1[j];
  }
#pragma unroll
  for (int off = 32; off; off >>= 1) {
    s  += __shfl_xor(s, off);
    sq += __shfl_xor(sq, off);
  }
  const float mu  = s * (1.f / 1024.f);
  const float var = sq * (1.f / 1024.f) - mu * mu;
  const float rs  = rsqrtf(var + 1e-5f);
  const float w   = wts[(size_t)(bbase + brow) * NEXP + e];

  const int c0 = lane * 8;
#pragma unroll
  for (int j = 0; j < 8; ++j) {
    const int ca = c0 + j, cb = 512 + c0 + j;
    zacc[e][ca] = w * ((f0[j] - mu) * rs * gamma[e * 1024 + ca] + beta[e * 1024 + ca]);
    zacc[e][cb] = w * ((f1[j] - mu) * rs * gamma[e * 1024 + cb] + beta[e * 1024 + cb]);
  }
  __syncthreads();
  float r0 = 0.f, r1 = 0.f;
#pragma unroll
  for (int ee = 0; ee < NEXP; ++ee) { r0 += zacc[ee][t]; r1 += zacc[ee][t + 512]; }
  float* zp = zout + (size_t)(bbase + brow) * 1024;
  zp[t] = r0;
  zp[t + 512] = r1;
}

// ---------------------------------------------------------------------------
extern "C" void kernel_launch(void* const* d_in, const int* in_sizes, int n_in,
                              void* d_out, int out_size, void* d_ws, size_t ws_size,
                              hipStream_t stream)
{
  const float* z_s      = (const float*)d_in[0];
  const float* z_e      = (const float*)d_in[1];
  const float* router_w = (const float*)d_in[2];
  const float* router_b = (const float*)d_in[3];
  const float* w1       = (const float*)d_in[4];
  const float* b1       = (const float*)d_in[5];
  const float* w2       = (const float*)d_in[6];
  const float* b2       = (const float*)d_in[7];
  const float* gamma    = (const float*)d_in[8];
  const float* beta     = (const float*)d_in[9];
  float* zout = (float*)d_out;

  const int B = 16384;

  // workspace layout
  char* ws = (char*)d_ws;
  unsigned short* Xb  = (unsigned short*)ws;                      // 33,554,432 B
  unsigned short* W1t = (unsigned short*)(ws + 33554432);         // 16,777,216 B
  unsigned short* W2t = W1t + ((size_t)8 << 20);                  // 16,777,216 B
  float* wts = (float*)(ws + 33554432 + 2 * 16777216);            //    524,288 B
  const size_t persist = 33554432 + 2 * 16777216 + 524288;
  char* dyn = ws + persist;
  const size_t rem = (ws_size > persist) ? (ws_size - persist) : 0;

  int nch = 1;
  while ((size_t)(B / nch) * 32768ull > rem && nch < 64) nch <<= 1;
  const int Bc = B / nch;   // multiple of 256

  unsigned short* hbuf = (unsigned short*)dyn;
  unsigned short* ybuf = hbuf + (size_t)Bc * 8 * 1024;

  cast_router_kernel<<<B, 256, 0, stream>>>(z_s, z_e, router_w, router_b, Xb, wts);
  wtrans_kernel<<<dim3(32, 32, 8), 256, 0, stream>>>(w1, W1t);
  wtrans_kernel<<<dim3(32, 32, 8), 256, 0, stream>>>(w2, W2t);

  const int mt = Bc >> 8;        // m-tiles of 256
  const int nwg = mt * 32;       // * 4 n-tiles * 8 experts

  for (int c = 0; c < nch; ++c) {
    const int bbase = c * Bc;
    gemm8_kernel<true><<<nwg, 512, 0, stream>>>(
        Xb + (size_t)bbase * 1024, W1t, b1, hbuf, 0ll, (long long)Bc * 1024, mt);
    gemm8_kernel<false><<<nwg, 512, 0, stream>>>(
        hbuf, W2t, b2, ybuf, (long long)Bc * 1024, (long long)Bc * 1024, mt);
    finalize_kernel<<<Bc, 512, 0, stream>>>(ybuf, wts, gamma, beta, zout, Bc, bbase);
  }
}

// Round 3
// 768.846 us; speedup vs baseline: 1.3196x; 1.0931x over previous
//
#include <hip/hip_runtime.h>
#include <cstdint>
#include <cstddef>

#define NEXP 8

typedef __attribute__((ext_vector_type(8))) short short8;
typedef __attribute__((ext_vector_type(4))) float f32x4;

static __device__ __forceinline__ float bf2f(unsigned short u) {
  union { unsigned int i; float f; } v; v.i = ((unsigned int)u) << 16; return v.f;
}
static __device__ __forceinline__ unsigned short f2bf(float f) {
  union { float f; unsigned int i; } v; v.f = f;
  unsigned int x = v.i;
  return (unsigned short)((x + 0x7fffu + ((x >> 16) & 1u)) >> 16);
}

// fast exact-enough GELU: tanh form, |err| <~1e-3 (below bf16 storage quant)
static __device__ __forceinline__ float gelu_fast(float x) {
  const float u = 0.7978845608028654f * (x + 0.044715f * x * x * x);
  // tanh(u) = 1 - 2/(exp(2u)+1)
  const float t = 1.0f - 2.0f / (__expf(2.0f * u) + 1.0f);
  return 0.5f * x * (1.0f + t);
}

__device__ __forceinline__ void gload16(const void* g, void* l) {
  __builtin_amdgcn_global_load_lds(
      (const __attribute__((address_space(1))) void*)g,
      (__attribute__((address_space(3))) void*)l, 16, 0, 0);
}

#define BAR() __builtin_amdgcn_s_barrier()
#define WAIT_LGKM0() asm volatile("s_waitcnt lgkmcnt(0)" ::: "memory")

// ---------------------------------------------------------------------------
// Kernel 1: cast concat(z_s,z_e) -> bf16 X, and compute router softmax (fp32)
// ---------------------------------------------------------------------------
__global__ __launch_bounds__(256) void cast_router_kernel(
    const float* __restrict__ z_s, const float* __restrict__ z_e,
    const float* __restrict__ rw, const float* __restrict__ rb,
    unsigned short* __restrict__ Xb, float* __restrict__ wts)
{
  const int b = blockIdx.x;
  const int t = threadIdx.x;

  const float* src = (t < 128) ? (z_s + (size_t)b * 512 + t * 4)
                               : (z_e + (size_t)b * 512 + (t - 128) * 4);
  float4 v = *(const float4*)src;

  ushort4 o;
  o.x = f2bf(v.x); o.y = f2bf(v.y); o.z = f2bf(v.z); o.w = f2bf(v.w);
  *(ushort4*)(Xb + (size_t)b * 1024 + t * 4) = o;

  float acc[NEXP];
#pragma unroll
  for (int e = 0; e < NEXP; ++e) acc[e] = 0.f;

  const int k0 = t * 4;
  const float xv[4] = { v.x, v.y, v.z, v.w };
#pragma unroll
  for (int j = 0; j < 4; ++j) {
    const float x = xv[j];
    const float4* rwp = (const float4*)(rw + (size_t)(k0 + j) * NEXP);
    float4 r0 = rwp[0], r1 = rwp[1];
    acc[0] += x * r0.x; acc[1] += x * r0.y; acc[2] += x * r0.z; acc[3] += x * r0.w;
    acc[4] += x * r1.x; acc[5] += x * r1.y; acc[6] += x * r1.z; acc[7] += x * r1.w;
  }

#pragma unroll
  for (int off = 32; off; off >>= 1) {
#pragma unroll
    for (int e = 0; e < NEXP; ++e) acc[e] += __shfl_xor(acc[e], off);
  }
  __shared__ float red[4][NEXP];
  if ((t & 63) == 0) {
#pragma unroll
    for (int e = 0; e < NEXP; ++e) red[t >> 6][e] = acc[e];
  }
  __syncthreads();
  if (t == 0) {
    float lg[NEXP];
    float mx = -1e30f;
#pragma unroll
    for (int e = 0; e < NEXP; ++e) {
      lg[e] = red[0][e] + red[1][e] + red[2][e] + red[3][e] + rb[e];
      mx = fmaxf(mx, lg[e]);
    }
    float sum = 0.f;
#pragma unroll
    for (int e = 0; e < NEXP; ++e) { lg[e] = expf(lg[e] - mx); sum += lg[e]; }
    const float inv = 1.f / sum;
#pragma unroll
    for (int e = 0; e < NEXP; ++e) wts[(size_t)b * NEXP + e] = lg[e] * inv;
  }
}

// ---------------------------------------------------------------------------
// Kernel 2: transpose+cast weights [E][K=1024][N=1024] fp32 -> [E][N][K] bf16
// merged: z in [0,16): z<8 -> w1, else w2
// ---------------------------------------------------------------------------
__global__ __launch_bounds__(256) void wtrans_kernel(
    const float* __restrict__ w1, const float* __restrict__ w2,
    unsigned short* __restrict__ wt1, unsigned short* __restrict__ wt2)
{
  __shared__ unsigned short tile[32][33];
  const int z = blockIdx.z;
  const float* w = (z < 8) ? w1 : w2;
  unsigned short* wt = (z < 8) ? wt1 : wt2;
  const int e = z & 7;
  const int k0 = blockIdx.y * 32, n0 = blockIdx.x * 32;
  const int tx = threadIdx.x & 31, ty = threadIdx.x >> 5;

  const float* wp = w + ((size_t)e << 20) + (size_t)k0 * 1024 + n0;
#pragma unroll
  for (int i = 0; i < 4; ++i) {
    const int kk = ty + i * 8;
    tile[kk][tx] = f2bf(wp[(size_t)kk * 1024 + tx]);
  }
  __syncthreads();
  unsigned short* op = wt + ((size_t)e << 20) + (size_t)n0 * 1024 + k0;
#pragma unroll
  for (int i = 0; i < 4; ++i) {
    const int nn = ty + i * 8;
    op[(size_t)nn * 1024 + tx] = tile[tx][nn];
  }
}

// ---------------------------------------------------------------------------
// Kernel 3: 256x256 8-phase bf16 GEMM (T1+T2+T3+T4+T5), K=1024 fixed.
// C[m][n] = A[m][:] . Bt[n][:] + bias[n]  (optional fast GELU)
// 512 threads = 8 waves (2M x 4N); per-wave 128x64 out; BK=64, NT=16, NI=8.
// LDS 128KB double-buffered; XOR swizzle via pre-swizzled global source.
// grid: 1D nwg = mtiles*4*8; XCD-bijective swizzle (nwg%8==0); with
// nwg=512,mt=16 each XCD owns exactly one expert's weight panel.
// ---------------------------------------------------------------------------
template <bool GELU>
__global__ __launch_bounds__(512, 2) void gemm8_kernel(
    const unsigned short* __restrict__ A,
    const unsigned short* __restrict__ Bt,
    const float* __restrict__ bias,
    unsigned short* __restrict__ C,
    long long strideAe, long long strideCe, int mtiles)
{
  __shared__ unsigned short lds[65536];  // 128 KB

  const int nwg = gridDim.x;
  const int cpx = nwg >> 3;
  const int bid = blockIdx.x;
  const int swz = (bid & 7) * cpx + (bid >> 3);
  const int e   = swz / (mtiles << 2);
  const int rem = swz - e * (mtiles << 2);
  const int m0  = (rem >> 2) << 8;
  const int n0  = (rem & 3) << 8;

  const int t   = threadIdx.x;
  const int l   = t & 63;
  const int wid = t >> 6;
  const int wm  = wid >> 2;   // 0..1
  const int wn  = wid & 3;    // 0..3

  const unsigned short* Ae = A + (size_t)e * strideAe + (size_t)m0 * 1024;
  const unsigned short* Be = Bt + ((size_t)e << 20) + (size_t)n0 * 1024;

  // staging: dest idx {t, t+512} of a 128x64 half-region (linear LDS dest;
  // source slot = destslot ^ (row&7))
  const int sr = t >> 3;
  const int ss = ((t & 7) ^ ((t >> 3) & 7)) * 8;

  auto stageA = [&](int d, int h, int T) {
    const unsigned short* g = Ae + (size_t)(h * 128 + sr) * 1024 + T * 64 + ss;
    unsigned short* lp = lds + d * 32768 + h * 8192 + t * 8;
    gload16(g, lp);
    gload16(g + 65536, lp + 4096);
  };
  auto stageB = [&](int d, int h, int T) {
    const unsigned short* g = Be + (size_t)(h * 128 + sr) * 1024 + T * 64 + ss;
    unsigned short* lp = lds + 16384 + d * 32768 + h * 8192 + t * 8;
    gload16(g, lp);
    gload16(g + 65536, lp + 4096);
  };

  // ds-read swizzled slots: wanted slot ks*4 + (l>>4), XOR (l&7)
  const int kq  = (l >> 4) ^ (l & 3);
  const int b2p = (l >> 2) & 1;
  const int sl0 = ((b2p << 2) | kq) * 8;
  const int sl1 = (((b2p ^ 1) << 2) | kq) * 8;
  const int aR = wm * 8192 + (l & 15) * 64;
  const int bR = 16384 + (wn >> 1) * 8192 + (wn & 1) * 4096 + (l & 15) * 64;

  short8 a[4][2], b0[2][2], b1[2][2];
  f32x4 acc[8][4];
#pragma unroll
  for (int i = 0; i < 8; ++i)
#pragma unroll
    for (int j = 0; j < 4; ++j) acc[i][j] = (f32x4){0.f, 0.f, 0.f, 0.f};

  auto ldA = [&](int d, int q) {
#pragma unroll
    for (int m = 0; m < 4; ++m) {
      const unsigned short* p = lds + d * 32768 + aR + (q * 4 + m) * 1024;
      a[m][0] = *(const short8*)(p + sl0);
      a[m][1] = *(const short8*)(p + sl1);
    }
  };
  auto ldB = [&](int d, int q, short8 (&br)[2][2]) {
#pragma unroll
    for (int n = 0; n < 2; ++n) {
      const unsigned short* p = lds + d * 32768 + bR + (q * 2 + n) * 1024;
      br[n][0] = *(const short8*)(p + sl0);
      br[n][1] = *(const short8*)(p + sl1);
    }
  };
  auto mmac = [&](int aq, int bq, short8 (&br)[2][2]) {
    __builtin_amdgcn_s_setprio(1);
#pragma unroll
    for (int ks = 0; ks < 2; ++ks)
#pragma unroll
      for (int m = 0; m < 4; ++m)
#pragma unroll
        for (int n = 0; n < 2; ++n)
          acc[aq * 4 + m][bq * 2 + n] = __builtin_amdgcn_mfma_f32_16x16x32_bf16(
              a[m][ks], br[n][ks], acc[aq * 4 + m][bq * 2 + n], 0, 0, 0);
    __builtin_amdgcn_s_setprio(0);
  };

  // prologue
  stageA(0, 0, 0); stageA(0, 1, 0); stageB(0, 0, 0); stageB(0, 1, 0);
  stageB(1, 0, 1); stageB(1, 1, 1); stageA(1, 0, 1);
  asm volatile("s_waitcnt vmcnt(6)" ::: "memory");
  BAR();

#pragma unroll 1
  for (int i = 0; i < 8; ++i) {
    const bool nl = (i < 7);
    const int T1 = 2 * i + 1, T2 = 2 * i + 2, T3 = 2 * i + 3;
    // P1
    ldA(0, 0); ldB(0, 0, b0); stageA(1, 1, T1);
    asm volatile("s_waitcnt lgkmcnt(8)" ::: "memory");
    BAR(); WAIT_LGKM0();
    mmac(0, 0, b0);
    BAR();
    // P2
    ldB(0, 1, b1);
    BAR(); WAIT_LGKM0();
    mmac(0, 1, b1);
    BAR();
    // P3
    ldA(0, 1);
    if (nl) stageB(0, 0, T2);
    BAR(); WAIT_LGKM0();
    mmac(1, 1, b1);
    BAR();
    // P4
    if (nl) { stageB(0, 1, T2); stageA(0, 0, T2); }
    BAR();
    mmac(1, 0, b0);
    if (nl) asm volatile("s_waitcnt vmcnt(6)" ::: "memory");
    else    asm volatile("s_waitcnt vmcnt(0)" ::: "memory");
    BAR();
    // P5
    ldA(1, 0); ldB(1, 0, b0);
    if (nl) stageA(0, 1, T2);
    asm volatile("s_waitcnt lgkmcnt(8)" ::: "memory");
    BAR(); WAIT_LGKM0();
    mmac(0, 0, b0);
    BAR();
    // P6
    ldB(1, 1, b1);
    BAR(); WAIT_LGKM0();
    mmac(0, 1, b1);
    BAR();
    // P7
    ldA(1, 1);
    if (nl) stageB(1, 0, T3);
    BAR(); WAIT_LGKM0();
    mmac(1, 1, b1);
    BAR();
    // P8
    if (nl) { stageB(1, 1, T3); stageA(1, 0, T3); }
    BAR();
    mmac(1, 0, b0);
    if (nl) asm volatile("s_waitcnt vmcnt(6)" ::: "memory");
    BAR();
  }

  // epilogue: C/D layout col = lane&15, row = (lane>>4)*4 + reg
  const float* bp = bias + (size_t)e * 1024 + n0 + wn * 64;
  unsigned short* Ce = C + (size_t)e * strideCe + (size_t)(m0 + wm * 128) * 1024 + n0 + wn * 64;
  const int cr = (l >> 4) * 4, cc = l & 15;
#pragma unroll
  for (int mi = 0; mi < 8; ++mi) {
#pragma unroll
    for (int ni = 0; ni < 4; ++ni) {
      const int col = ni * 16 + cc;
      const float bv = bp[col];
#pragma unroll
      for (int r = 0; r < 4; ++r) {
        float v = acc[mi][ni][r] + bv;
        if (GELU) v = gelu_fast(v);
        Ce[(size_t)(mi * 16 + cr + r) * 1024 + col] = f2bf(v);
      }
    }
  }
}

// ---------------------------------------------------------------------------
// Kernel 4: per-expert LayerNorm + softmax-weighted sum over experts
// ---------------------------------------------------------------------------
__global__ __launch_bounds__(512) void finalize_kernel(
    const unsigned short* __restrict__ y,   // [E][Bc][1024] bf16
    const float* __restrict__ wts,
    const float* __restrict__ gamma,
    const float* __restrict__ beta,
    float* __restrict__ zout,
    int Bc, int bbase)
{
  __shared__ float zacc[NEXP][1024];
  const int brow = blockIdx.x;
  const int t = threadIdx.x;
  const int e = t >> 6;
  const int lane = t & 63;

  const unsigned short* yp = y + ((size_t)e * Bc + brow) * 1024;
  short8 v0 = *(const short8*)(yp + lane * 8);
  short8 v1 = *(const short8*)(yp + 512 + lane * 8);

  float f0[8], f1[8];
  float s = 0.f, sq = 0.f;
#pragma unroll
  for (int j = 0; j < 8; ++j) {
    f0[j] = bf2f((unsigned short)v0[j]);
    f1[j] = bf2f((unsigned short)v1[j]);
    s += f0[j] + f1[j];
    sq += f0[j] * f0[j] + f1[j] * f1[j];
  }
#pragma unroll
  for (int off = 32; off; off >>= 1) {
    s  += __shfl_xor(s, off);
    sq += __shfl_xor(sq, off);
  }
  const float mu  = s * (1.f / 1024.f);
  const float var = sq * (1.f / 1024.f) - mu * mu;
  const float rs  = rsqrtf(var + 1e-5f);
  const float w   = wts[(size_t)(bbase + brow) * NEXP + e];

  const int c0 = lane * 8;
#pragma unroll
  for (int j = 0; j < 8; ++j) {
    const int ca = c0 + j, cb = 512 + c0 + j;
    zacc[e][ca] = w * ((f0[j] - mu) * rs * gamma[e * 1024 + ca] + beta[e * 1024 + ca]);
    zacc[e][cb] = w * ((f1[j] - mu) * rs * gamma[e * 1024 + cb] + beta[e * 1024 + cb]);
  }
  __syncthreads();
  float r0 = 0.f, r1 = 0.f;
#pragma unroll
  for (int ee = 0; ee < NEXP; ++ee) { r0 += zacc[ee][t]; r1 += zacc[ee][t + 512]; }
  float* zp = zout + (size_t)(bbase + brow) * 1024;
  zp[t] = r0;
  zp[t + 512] = r1;
}

// ---------------------------------------------------------------------------
extern "C" void kernel_launch(void* const* d_in, const int* in_sizes, int n_in,
                              void* d_out, int out_size, void* d_ws, size_t ws_size,
                              hipStream_t stream)
{
  const float* z_s      = (const float*)d_in[0];
  const float* z_e      = (const float*)d_in[1];
  const float* router_w = (const float*)d_in[2];
  const float* router_b = (const float*)d_in[3];
  const float* w1       = (const float*)d_in[4];
  const float* b1       = (const float*)d_in[5];
  const float* w2       = (const float*)d_in[6];
  const float* b2       = (const float*)d_in[7];
  const float* gamma    = (const float*)d_in[8];
  const float* beta     = (const float*)d_in[9];
  float* zout = (float*)d_out;

  const int B = 16384;

  // workspace layout
  char* ws = (char*)d_ws;
  unsigned short* Xb  = (unsigned short*)ws;                      // 33,554,432 B
  unsigned short* W1t = (unsigned short*)(ws + 33554432);         // 16,777,216 B
  unsigned short* W2t = W1t + ((size_t)8 << 20);                  // 16,777,216 B
  float* wts = (float*)(ws + 33554432 + 2 * 16777216);            //    524,288 B
  const size_t persist = 33554432 + 2 * 16777216 + 524288;
  char* dyn = ws + persist;
  const size_t rem = (ws_size > persist) ? (ws_size - persist) : 0;

  // chunk so h+y stay L3-resident (Bc=4096 -> 134 MB); grow nch if ws small
  int nch = 4;
  while ((size_t)(B / nch) * 32768ull > rem && nch < 64) nch <<= 1;
  const int Bc = B / nch;   // multiple of 256

  unsigned short* hbuf = (unsigned short*)dyn;
  unsigned short* ybuf = hbuf + (size_t)Bc * 8 * 1024;

  cast_router_kernel<<<B, 256, 0, stream>>>(z_s, z_e, router_w, router_b, Xb, wts);
  wtrans_kernel<<<dim3(32, 32, 16), 256, 0, stream>>>(w1, w2, W1t, W2t);

  const int mt = Bc >> 8;        // m-tiles of 256
  const int nwg = mt * 32;       // * 4 n-tiles * 8 experts

  for (int c = 0; c < nch; ++c) {
    const int bbase = c * Bc;
    gemm8_kernel<true><<<nwg, 512, 0, stream>>>(
        Xb + (size_t)bbase * 1024, W1t, b1, hbuf, 0ll, (long long)Bc * 1024, mt);
    gemm8_kernel<false><<<nwg, 512, 0, stream>>>(
        hbuf, W2t, b2, ybuf, (long long)Bc * 1024, (long long)Bc * 1024, mt);
    finalize_kernel<<<Bc, 512, 0, stream>>>(ybuf, wts, gamma, beta, zout, Bc, bbase);
  }
}

// Round 4
// 762.877 us; speedup vs baseline: 1.3299x; 1.0078x over previous
//
#include <hip/hip_runtime.h>
#include <cstdint>
#include <cstddef>

#define NEXP 8

typedef __attribute__((ext_vector_type(8))) short short8;
typedef __attribute__((ext_vector_type(4))) float f32x4;

static __device__ __forceinline__ float bf2f(unsigned short u) {
  union { unsigned int i; float f; } v; v.i = ((unsigned int)u) << 16; return v.f;
}
static __device__ __forceinline__ unsigned short f2bf(float f) {
  union { float f; unsigned int i; } v; v.f = f;
  unsigned int x = v.i;
  return (unsigned short)((x + 0x7fffu + ((x >> 16) & 1u)) >> 16);
}

// fast exact-enough GELU: tanh form, |err| <~1e-3 (below bf16 storage quant)
static __device__ __forceinline__ float gelu_fast(float x) {
  const float u = 0.7978845608028654f * (x + 0.044715f * x * x * x);
  const float t = 1.0f - 2.0f / (__expf(2.0f * u) + 1.0f);
  return 0.5f * x * (1.0f + t);
}

__device__ __forceinline__ void gload16(const void* g, void* l) {
  __builtin_amdgcn_global_load_lds(
      (const __attribute__((address_space(1))) void*)g,
      (__attribute__((address_space(3))) void*)l, 16, 0, 0);
}

#define BAR() __builtin_amdgcn_s_barrier()
#define WAIT_LGKM0() asm volatile("s_waitcnt lgkmcnt(0)" ::: "memory")

// ---------------------------------------------------------------------------
// Kernel 1 (merged prep): blocks [0,16384): cast concat row -> bf16 X + router
// softmax; blocks [16384, 32768): transpose+cast w1/w2 -> [E][N][K] bf16.
// ---------------------------------------------------------------------------
__global__ __launch_bounds__(256) void prep_kernel(
    const float* __restrict__ z_s, const float* __restrict__ z_e,
    const float* __restrict__ rw, const float* __restrict__ rb,
    const float* __restrict__ w1, const float* __restrict__ w2,
    unsigned short* __restrict__ Xb, float* __restrict__ wts,
    unsigned short* __restrict__ wt1, unsigned short* __restrict__ wt2)
{
  __shared__ float red[4][NEXP];
  __shared__ unsigned short tile[32][33];
  const int bid = blockIdx.x;
  const int t = threadIdx.x;

  if (bid < 16384) {
    const int b = bid;
    const float* src = (t < 128) ? (z_s + (size_t)b * 512 + t * 4)
                                 : (z_e + (size_t)b * 512 + (t - 128) * 4);
    float4 v = *(const float4*)src;

    ushort4 o;
    o.x = f2bf(v.x); o.y = f2bf(v.y); o.z = f2bf(v.z); o.w = f2bf(v.w);
    *(ushort4*)(Xb + (size_t)b * 1024 + t * 4) = o;

    float acc[NEXP];
#pragma unroll
    for (int e = 0; e < NEXP; ++e) acc[e] = 0.f;

    const int k0 = t * 4;
    const float xv[4] = { v.x, v.y, v.z, v.w };
#pragma unroll
    for (int j = 0; j < 4; ++j) {
      const float x = xv[j];
      const float4* rwp = (const float4*)(rw + (size_t)(k0 + j) * NEXP);
      float4 r0 = rwp[0], r1 = rwp[1];
      acc[0] += x * r0.x; acc[1] += x * r0.y; acc[2] += x * r0.z; acc[3] += x * r0.w;
      acc[4] += x * r1.x; acc[5] += x * r1.y; acc[6] += x * r1.z; acc[7] += x * r1.w;
    }

#pragma unroll
    for (int off = 32; off; off >>= 1) {
#pragma unroll
      for (int e = 0; e < NEXP; ++e) acc[e] += __shfl_xor(acc[e], off);
    }
    if ((t & 63) == 0) {
#pragma unroll
      for (int e = 0; e < NEXP; ++e) red[t >> 6][e] = acc[e];
    }
    __syncthreads();
    if (t == 0) {
      float lg[NEXP];
      float mx = -1e30f;
#pragma unroll
      for (int e = 0; e < NEXP; ++e) {
        lg[e] = red[0][e] + red[1][e] + red[2][e] + red[3][e] + rb[e];
        mx = fmaxf(mx, lg[e]);
      }
      float sum = 0.f;
#pragma unroll
      for (int e = 0; e < NEXP; ++e) { lg[e] = expf(lg[e] - mx); sum += lg[e]; }
      const float inv = 1.f / sum;
#pragma unroll
      for (int e = 0; e < NEXP; ++e) wts[(size_t)b * NEXP + e] = lg[e] * inv;
    }
  } else {
    const int z = (bid - 16384) >> 10;            // 0..15
    const int r = (bid - 16384) & 1023;
    const int k0 = (r >> 5) * 32, n0 = (r & 31) * 32;
    const float* w = (z < 8) ? w1 : w2;
    unsigned short* wt = (z < 8) ? wt1 : wt2;
    const int e = z & 7;
    const int tx = t & 31, ty = t >> 5;

    const float* wp = w + ((size_t)e << 20) + (size_t)k0 * 1024 + n0;
#pragma unroll
    for (int i = 0; i < 4; ++i) {
      const int kk = ty + i * 8;
      tile[kk][tx] = f2bf(wp[(size_t)kk * 1024 + tx]);
    }
    __syncthreads();
    unsigned short* op = wt + ((size_t)e << 20) + (size_t)n0 * 1024 + k0;
#pragma unroll
    for (int i = 0; i < 4; ++i) {
      const int nn = ty + i * 8;
      op[(size_t)nn * 1024 + tx] = tile[tx][nn];
    }
  }
}

// ---------------------------------------------------------------------------
// Kernel 2: 256x256 8-phase bf16 GEMM (T1+T2+T3+T4+T5), K=1024 fixed.
// C[m][n] = A[m][:] . Bt[n][:] + bias[n]  (optional fast GELU)
// 512 threads = 8 waves (2M x 4N); per-wave 128x64 out; BK=64, NT=16, NI=8.
// LDS 128KB double-buffered; XOR swizzle via pre-swizzled global source.
// grid: 1D nwg = mtiles*4*8; XCD-bijective swizzle (nwg%8==0).
// ---------------------------------------------------------------------------
template <bool GELU>
__global__ __launch_bounds__(512, 2) void gemm8_kernel(
    const unsigned short* __restrict__ A,
    const unsigned short* __restrict__ Bt,
    const float* __restrict__ bias,
    unsigned short* __restrict__ C,
    long long strideAe, long long strideCe, int mtiles)
{
  __shared__ unsigned short lds[65536];  // 128 KB

  const int nwg = gridDim.x;
  const int cpx = nwg >> 3;
  const int bid = blockIdx.x;
  const int swz = (bid & 7) * cpx + (bid >> 3);
  const int e   = swz / (mtiles << 2);
  const int rem = swz - e * (mtiles << 2);
  const int m0  = (rem >> 2) << 8;
  const int n0  = (rem & 3) << 8;

  const int t   = threadIdx.x;
  const int l   = t & 63;
  const int wid = t >> 6;
  const int wm  = wid >> 2;   // 0..1
  const int wn  = wid & 3;    // 0..3

  const unsigned short* Ae = A + (size_t)e * strideAe + (size_t)m0 * 1024;
  const unsigned short* Be = Bt + ((size_t)e << 20) + (size_t)n0 * 1024;

  // staging: dest idx {t, t+512} of a 128x64 half-region (linear LDS dest;
  // source slot = destslot ^ (row&7))
  const int sr = t >> 3;
  const int ss = ((t & 7) ^ ((t >> 3) & 7)) * 8;

  auto stageA = [&](int d, int h, int T) {
    const unsigned short* g = Ae + (size_t)(h * 128 + sr) * 1024 + T * 64 + ss;
    unsigned short* lp = lds + d * 32768 + h * 8192 + t * 8;
    gload16(g, lp);
    gload16(g + 65536, lp + 4096);
  };
  auto stageB = [&](int d, int h, int T) {
    const unsigned short* g = Be + (size_t)(h * 128 + sr) * 1024 + T * 64 + ss;
    unsigned short* lp = lds + 16384 + d * 32768 + h * 8192 + t * 8;
    gload16(g, lp);
    gload16(g + 65536, lp + 4096);
  };

  // ds-read swizzled slots: wanted slot ks*4 + (l>>4), XOR (l&7)
  const int kq  = (l >> 4) ^ (l & 3);
  const int b2p = (l >> 2) & 1;
  const int sl0 = ((b2p << 2) | kq) * 8;
  const int sl1 = (((b2p ^ 1) << 2) | kq) * 8;
  const int aR = wm * 8192 + (l & 15) * 64;
  const int bR = 16384 + (wn >> 1) * 8192 + (wn & 1) * 4096 + (l & 15) * 64;

  short8 a[4][2], b0[2][2], b1[2][2];
  f32x4 acc[8][4];
#pragma unroll
  for (int i = 0; i < 8; ++i)
#pragma unroll
    for (int j = 0; j < 4; ++j) acc[i][j] = (f32x4){0.f, 0.f, 0.f, 0.f};

  auto ldA = [&](int d, int q) {
#pragma unroll
    for (int m = 0; m < 4; ++m) {
      const unsigned short* p = lds + d * 32768 + aR + (q * 4 + m) * 1024;
      a[m][0] = *(const short8*)(p + sl0);
      a[m][1] = *(const short8*)(p + sl1);
    }
  };
  auto ldB = [&](int d, int q, short8 (&br)[2][2]) {
#pragma unroll
    for (int n = 0; n < 2; ++n) {
      const unsigned short* p = lds + d * 32768 + bR + (q * 2 + n) * 1024;
      br[n][0] = *(const short8*)(p + sl0);
      br[n][1] = *(const short8*)(p + sl1);
    }
  };
  auto mmac = [&](int aq, int bq, short8 (&br)[2][2]) {
    __builtin_amdgcn_s_setprio(1);
#pragma unroll
    for (int ks = 0; ks < 2; ++ks)
#pragma unroll
      for (int m = 0; m < 4; ++m)
#pragma unroll
        for (int n = 0; n < 2; ++n)
          acc[aq * 4 + m][bq * 2 + n] = __builtin_amdgcn_mfma_f32_16x16x32_bf16(
              a[m][ks], br[n][ks], acc[aq * 4 + m][bq * 2 + n], 0, 0, 0);
    __builtin_amdgcn_s_setprio(0);
  };

  // prologue
  stageA(0, 0, 0); stageA(0, 1, 0); stageB(0, 0, 0); stageB(0, 1, 0);
  stageB(1, 0, 1); stageB(1, 1, 1); stageA(1, 0, 1);
  asm volatile("s_waitcnt vmcnt(6)" ::: "memory");
  BAR();

#pragma unroll 1
  for (int i = 0; i < 8; ++i) {
    const bool nl = (i < 7);
    const int T1 = 2 * i + 1, T2 = 2 * i + 2, T3 = 2 * i + 3;
    // P1
    ldA(0, 0); ldB(0, 0, b0); stageA(1, 1, T1);
    asm volatile("s_waitcnt lgkmcnt(8)" ::: "memory");
    BAR(); WAIT_LGKM0();
    mmac(0, 0, b0);
    BAR();
    // P2
    ldB(0, 1, b1);
    BAR(); WAIT_LGKM0();
    mmac(0, 1, b1);
    BAR();
    // P3
    ldA(0, 1);
    if (nl) stageB(0, 0, T2);
    BAR(); WAIT_LGKM0();
    mmac(1, 1, b1);
    BAR();
    // P4
    if (nl) { stageB(0, 1, T2); stageA(0, 0, T2); }
    BAR();
    mmac(1, 0, b0);
    if (nl) asm volatile("s_waitcnt vmcnt(6)" ::: "memory");
    else    asm volatile("s_waitcnt vmcnt(0)" ::: "memory");
    BAR();
    // P5
    ldA(1, 0); ldB(1, 0, b0);
    if (nl) stageA(0, 1, T2);
    asm volatile("s_waitcnt lgkmcnt(8)" ::: "memory");
    BAR(); WAIT_LGKM0();
    mmac(0, 0, b0);
    BAR();
    // P6
    ldB(1, 1, b1);
    BAR(); WAIT_LGKM0();
    mmac(0, 1, b1);
    BAR();
    // P7
    ldA(1, 1);
    if (nl) stageB(1, 0, T3);
    BAR(); WAIT_LGKM0();
    mmac(1, 1, b1);
    BAR();
    // P8
    if (nl) { stageB(1, 1, T3); stageA(1, 0, T3); }
    BAR();
    mmac(1, 0, b0);
    if (nl) asm volatile("s_waitcnt vmcnt(6)" ::: "memory");
    BAR();
  }

  // epilogue: C/D layout col = lane&15, row = (lane>>4)*4 + reg
  const float* bp = bias + (size_t)e * 1024 + n0 + wn * 64;
  unsigned short* Ce = C + (size_t)e * strideCe + (size_t)(m0 + wm * 128) * 1024 + n0 + wn * 64;
  const int cr = (l >> 4) * 4, cc = l & 15;
#pragma unroll
  for (int mi = 0; mi < 8; ++mi) {
#pragma unroll
    for (int ni = 0; ni < 4; ++ni) {
      const int col = ni * 16 + cc;
      const float bv = bp[col];
#pragma unroll
      for (int r = 0; r < 4; ++r) {
        float v = acc[mi][ni][r] + bv;
        if (GELU) v = gelu_fast(v);
        Ce[(size_t)(mi * 16 + cr + r) * 1024 + col] = f2bf(v);
      }
    }
  }
}

// ---------------------------------------------------------------------------
// Kernel 3: per-expert LayerNorm + softmax-weighted sum over experts
// ---------------------------------------------------------------------------
__global__ __launch_bounds__(512) void finalize_kernel(
    const unsigned short* __restrict__ y,   // [E][Bc][1024] bf16
    const float* __restrict__ wts,
    const float* __restrict__ gamma,
    const float* __restrict__ beta,
    float* __restrict__ zout,
    int Bc, int bbase)
{
  __shared__ float zacc[NEXP][1024];
  const int brow = blockIdx.x;
  const int t = threadIdx.x;
  const int e = t >> 6;
  const int lane = t & 63;

  const unsigned short* yp = y + ((size_t)e * Bc + brow) * 1024;
  short8 v0 = *(const short8*)(yp + lane * 8);
  short8 v1 = *(const short8*)(yp + 512 + lane * 8);

  float f0[8], f1[8];
  float s = 0.f, sq = 0.f;
#pragma unroll
  for (int j = 0; j < 8; ++j) {
    f0[j] = bf2f((unsigned short)v0[j]);
    f1[j] = bf2f((unsigned short)v1[j]);
    s += f0[j] + f1[j];
    sq += f0[j] * f0[j] + f1[j] * f1[j];
  }
#pragma unroll
  for (int off = 32; off; off >>= 1) {
    s  += __shfl_xor(s, off);
    sq += __shfl_xor(sq, off);
  }
  const float mu  = s * (1.f / 1024.f);
  const float var = sq * (1.f / 1024.f) - mu * mu;
  const float rs  = rsqrtf(var + 1e-5f);
  const float w   = wts[(size_t)(bbase + brow) * NEXP + e];

  const int c0 = lane * 8;
#pragma unroll
  for (int j = 0; j < 8; ++j) {
    const int ca = c0 + j, cb = 512 + c0 + j;
    zacc[e][ca] = w * ((f0[j] - mu) * rs * gamma[e * 1024 + ca] + beta[e * 1024 + ca]);
    zacc[e][cb] = w * ((f1[j] - mu) * rs * gamma[e * 1024 + cb] + beta[e * 1024 + cb]);
  }
  __syncthreads();
  float r0 = 0.f, r1 = 0.f;
#pragma unroll
  for (int ee = 0; ee < NEXP; ++ee) { r0 += zacc[ee][t]; r1 += zacc[ee][t + 512]; }
  float* zp = zout + (size_t)(bbase + brow) * 1024;
  zp[t] = r0;
  zp[t + 512] = r1;
}

// ---------------------------------------------------------------------------
extern "C" void kernel_launch(void* const* d_in, const int* in_sizes, int n_in,
                              void* d_out, int out_size, void* d_ws, size_t ws_size,
                              hipStream_t stream)
{
  const float* z_s      = (const float*)d_in[0];
  const float* z_e      = (const float*)d_in[1];
  const float* router_w = (const float*)d_in[2];
  const float* router_b = (const float*)d_in[3];
  const float* w1       = (const float*)d_in[4];
  const float* b1       = (const float*)d_in[5];
  const float* w2       = (const float*)d_in[6];
  const float* b2       = (const float*)d_in[7];
  const float* gamma    = (const float*)d_in[8];
  const float* beta     = (const float*)d_in[9];
  float* zout = (float*)d_out;

  const int B = 16384;

  // workspace layout
  char* ws = (char*)d_ws;
  unsigned short* Xb  = (unsigned short*)ws;                      // 33,554,432 B
  unsigned short* W1t = (unsigned short*)(ws + 33554432);         // 16,777,216 B
  unsigned short* W2t = W1t + ((size_t)8 << 20);                  // 16,777,216 B
  float* wts = (float*)(ws + 33554432 + 2 * 16777216);            //    524,288 B
  const size_t persist = 33554432 + 2 * 16777216 + 524288;
  char* dyn = ws + persist;
  const size_t rem = (ws_size > persist) ? (ws_size - persist) : 0;

  // nch=2 (Bc=8192): fewest dispatch boundaries that fit ws; h largely
  // L3-resident anyway (round-2 FETCH evidence). Grow nch if ws is small.
  int nch = 2;
  while ((size_t)(B / nch) * 32768ull > rem && nch < 64) nch <<= 1;
  const int Bc = B / nch;   // multiple of 256

  unsigned short* hbuf = (unsigned short*)dyn;
  unsigned short* ybuf = hbuf + (size_t)Bc * 8 * 1024;

  prep_kernel<<<32768, 256, 0, stream>>>(z_s, z_e, router_w, router_b, w1, w2,
                                         Xb, wts, W1t, W2t);

  const int mt = Bc >> 8;        // m-tiles of 256
  const int nwg = mt * 32;       // * 4 n-tiles * 8 experts

  for (int c = 0; c < nch; ++c) {
    const int bbase = c * Bc;
    gemm8_kernel<true><<<nwg, 512, 0, stream>>>(
        Xb + (size_t)bbase * 1024, W1t, b1, hbuf, 0ll, (long long)Bc * 1024, mt);
    gemm8_kernel<false><<<nwg, 512, 0, stream>>>(
        hbuf, W2t, b2, ybuf, (long long)Bc * 1024, (long long)Bc * 1024, mt);
    finalize_kernel<<<Bc, 512, 0, stream>>>(ybuf, wts, gamma, beta, zout, Bc, bbase);
  }
}